// Round 1
// baseline (350.736 us; speedup 1.0000x reference)
//
#include <hip/hip_runtime.h>
#include <cstdint>
#include <cstddef>

// Problem constants: B=2, S=2048, D=1024, H=16, dk=64. M = B*S = 4096.
#define S_LEN 2048
#define NH    16
#define DKH   64
#define DEMB  1024
#define MTOT  4096

typedef float f32x4 __attribute__((ext_vector_type(4)));
typedef __bf16 bf16x8 __attribute__((ext_vector_type(8)));
typedef unsigned short u16;
typedef u16 u16x8 __attribute__((ext_vector_type(8)));
typedef u16 u16x4 __attribute__((ext_vector_type(4)));

static __device__ __forceinline__ u16 f2bf(float f) {
  unsigned int u = __builtin_bit_cast(unsigned int, f);
  u += 0x7fffu + ((u >> 16) & 1u);          // RNE
  return (u16)(u >> 16);
}
static __device__ __forceinline__ float bf2f(u16 b) {
  return __builtin_bit_cast(float, ((unsigned int)b) << 16);
}
static __device__ __forceinline__ bf16x8 ldfrag(const u16* p) {
  return __builtin_bit_cast(bf16x8, *(const u16x8*)p);
}
static __device__ __forceinline__ f32x4 mfma16(bf16x8 a, bf16x8 b, f32x4 c) {
  return __builtin_amdgcn_mfma_f32_16x16x32_bf16(a, b, c, 0, 0, 0);
}
static __device__ __forceinline__ void gl2lds16(const void* g, void* l) {
  __builtin_amdgcn_global_load_lds((__attribute__((address_space(1))) void*)g,
                                   (__attribute__((address_space(3))) void*)l,
                                   16, 0, 0);
}

// ---------------- fp32 -> bf16 convert (weights) ----------------
__global__ __launch_bounds__(256) void cvt_bf16(const float* __restrict__ s,
                                                u16* __restrict__ d, int n) {
  int i = (blockIdx.x * 256 + threadIdx.x) * 4;
  if (i >= n) return;
  f32x4 f = *(const f32x4*)(s + i);
  u16x4 o;
  o[0] = f2bf(f[0]); o[1] = f2bf(f[1]); o[2] = f2bf(f[2]); o[3] = f2bf(f[3]);
  *(u16x4*)(d + i) = o;
}

// ---------------- fused QKV projection GEMM ----------------
// C[m,n] = A[m,:] . W[n,:] + bias[n].  A in {Q,K,V} selected per 1024-col
// segment. 128x128 tile, BK=32, 256 thr (4 waves, 2x2 of 64x64 per wave,
// 4x4 grid of 16x16x32 MFMAs). A staged fp32->bf16 through regs; W via
// global_load_lds (16B). LDS col-chunks XOR-swizzled to spread banks.
__global__ __launch_bounds__(256) void qkv_gemm(
    const float* __restrict__ Qm, const float* __restrict__ Km,
    const float* __restrict__ Vm, const u16* __restrict__ W,
    const float* __restrict__ bq, const float* __restrict__ bk,
    const float* __restrict__ bv,
    u16* __restrict__ qh, u16* __restrict__ kh, u16* __restrict__ vt) {
  __shared__ __align__(16) u16 sA[128 * 32];
  __shared__ __align__(16) u16 sB[128 * 32];
  const int t = threadIdx.x;
  const int l = t & 63, w = t >> 6;
  const int ll = l & 15, lg = l >> 4;
  const int nb = blockIdx.x;           // 0..23 (N = 3072)
  const int mb = blockIdx.y;           // 0..31 (M = 4096)
  const int which = nb >> 3;           // 0=Q,1=K,2=V
  const float* A = (which == 0) ? Qm : ((which == 1) ? Km : Vm);
  const int wr = (w >> 1) * 64, wc = (w & 1) * 64;

  f32x4 acc[4][4] = {};

  for (int kt = 0; kt < 32; ++kt) {
    const int k0 = kt * 32;
    __syncthreads();
#pragma unroll
    for (int i = 0; i < 2; ++i) {
      const int c = i * 256 + t;                 // physical 16B chunk 0..511
      const int row = c >> 2;                    // 0..127
      const int pc = c & 3;                      // physical col-chunk
      const int gc = pc ^ ((row ^ (row >> 2)) & 3);  // logical col-chunk
      // A: fp32 load + convert
      const float* src = A + (size_t)(mb * 128 + row) * DEMB + k0 + gc * 8;
      f32x4 f0 = *(const f32x4*)src;
      f32x4 f1 = *(const f32x4*)(src + 4);
      u16x8 v;
      v[0] = f2bf(f0[0]); v[1] = f2bf(f0[1]); v[2] = f2bf(f0[2]); v[3] = f2bf(f0[3]);
      v[4] = f2bf(f1[0]); v[5] = f2bf(f1[1]); v[6] = f2bf(f1[2]); v[7] = f2bf(f1[3]);
      *(u16x8*)&sA[c * 8] = v;
      // B: async bf16
      gl2lds16(W + (size_t)(nb * 128 + row) * DEMB + k0 + gc * 8, &sB[c * 8]);
    }
    __syncthreads();

    bf16x8 af[4], bfr[4];
#pragma unroll
    for (int i2 = 0; i2 < 4; ++i2) {
      const int row = wr + i2 * 16 + ll;
      const int p = lg ^ ((row ^ (row >> 2)) & 3);
      af[i2] = ldfrag(&sA[row * 32 + p * 8]);
    }
#pragma unroll
    for (int j2 = 0; j2 < 4; ++j2) {
      const int row = wc + j2 * 16 + ll;
      const int p = lg ^ ((row ^ (row >> 2)) & 3);
      bfr[j2] = ldfrag(&sB[row * 32 + p * 8]);
    }
#pragma unroll
    for (int i2 = 0; i2 < 4; ++i2)
#pragma unroll
      for (int j2 = 0; j2 < 4; ++j2)
        acc[i2][j2] = mfma16(af[i2], bfr[j2], acc[i2][j2]);
  }

  const float* bias = (which == 0) ? bq : ((which == 1) ? bk : bv);
  u16* outp = (which == 0) ? qh : ((which == 1) ? kh : vt);
#pragma unroll
  for (int j2 = 0; j2 < 4; ++j2) {
    const int ncol = nb * 128 + wc + j2 * 16 + ll;
    const int nl = ncol & 1023;                  // within-segment column
    const int h = nl >> 6, dk = nl & 63;
    const float bb = bias[nl];
#pragma unroll
    for (int i2 = 0; i2 < 4; ++i2) {
#pragma unroll
      for (int r = 0; r < 4; ++r) {
        const int mrow = mb * 128 + wr + i2 * 16 + lg * 4 + r;
        const int b = mrow >> 11, s = mrow & 2047;
        const float val = acc[i2][j2][r] + bb;
        size_t idx;
        if (which == 2)   // v transposed: [BH][dk][S]
          idx = ((size_t)((b * NH + h) * DKH + dk)) * S_LEN + s;
        else              // q,k: [BH][S][dk]
          idx = ((size_t)((b * NH + h) * S_LEN + s)) * DKH + dk;
        outp[idx] = f2bf(val);
      }
    }
  }
}

// ---------------- flash attention ----------------
// One block = one (b,h), 64 q-rows (wave w owns rows q0+w*16..+16).
// Loop over 32 key tiles of 64. sK [64 key][64 dk], sV [64 dk][64 key],
// both XOR-swizzled per 16B chunk (8 chunks/row) -> conflict-free frags.
__global__ __launch_bounds__(256) void attn_kernel(
    const u16* __restrict__ qh, const u16* __restrict__ kh,
    const u16* __restrict__ vt, u16* __restrict__ ctx) {
  __shared__ __align__(16) u16 sK[64 * 64];
  __shared__ __align__(16) u16 sV[64 * 64];
  __shared__ __align__(16) u16 sP[4][16 * 64];
  const int t = threadIdx.x;
  const int l = t & 63, w = t >> 6;
  const int ll = l & 15, lg = l >> 4;
  const int q0 = blockIdx.x * 64;
  const int bh = blockIdx.y;

  // Q fragments (held in regs for the whole loop)
  const u16* qbase = qh + ((size_t)bh * S_LEN + q0 + w * 16 + ll) * DKH;
  const bf16x8 aq0 = ldfrag(qbase + lg * 8);
  const bf16x8 aq1 = ldfrag(qbase + 32 + lg * 8);

  const float SCL = 0.125f * 1.44269504088896340736f;  // 1/sqrt(dk) * log2(e)
  float m_run[4] = {-1e30f, -1e30f, -1e30f, -1e30f};
  float l_run[4] = {0.f, 0.f, 0.f, 0.f};
  f32x4 o_acc[4] = {};

  for (int kt = 0; kt < 32; ++kt) {
    __syncthreads();
#pragma unroll
    for (int i = 0; i < 2; ++i) {
      const int c = i * 256 + t;        // 0..511
      const int row = c >> 3;           // 0..63
      const int pc = c & 7;
      const int gc = pc ^ (row & 7);
      gl2lds16(kh + ((size_t)bh * S_LEN + kt * 64 + row) * DKH + gc * 8,
               &sK[c * 8]);
      gl2lds16(vt + ((size_t)bh * DKH + row) * S_LEN + kt * 64 + gc * 8,
               &sV[c * 8]);
    }
    __syncthreads();

    // S = Q K^T  (C layout: row = lg*4+r, col(key) = c*16+ll)
    f32x4 sc4[4];
#pragma unroll
    for (int c = 0; c < 4; ++c) {
      const int row = c * 16 + ll;
      const int p0 = (0 + lg) ^ (row & 7);
      const int p1 = (4 + lg) ^ (row & 7);
      f32x4 z = {};
      z = mfma16(aq0, ldfrag(&sK[row * 64 + p0 * 8]), z);
      z = mfma16(aq1, ldfrag(&sK[row * 64 + p1 * 8]), z);
      sc4[c] = z;
    }

    // online softmax in exp2 domain
    float al[4];
#pragma unroll
    for (int r = 0; r < 4; ++r) {
      float mx = fmaxf(fmaxf(sc4[0][r], sc4[1][r]), fmaxf(sc4[2][r], sc4[3][r]));
#pragma unroll
      for (int msk = 1; msk < 16; msk <<= 1)
        mx = fmaxf(mx, __shfl_xor(mx, msk, 64));
      mx *= SCL;
      const float mn = fmaxf(m_run[r], mx);
      al[r] = __builtin_amdgcn_exp2f(m_run[r] - mn);
      m_run[r] = mn;
      const int pr = lg * 4 + r;
      float psum = 0.f;
#pragma unroll
      for (int c = 0; c < 4; ++c) {
        const float p = __builtin_amdgcn_exp2f(sc4[c][r] * SCL - mn);
        const u16 pb = f2bf(p);
        psum += bf2f(pb);       // keep l consistent with bf16 P fed to PV
        const int pc = c * 16 + ll;
        sP[w][pr * 64 + ((((pc >> 3) ^ (pr & 7)) << 3) | (pc & 7))] = pb;
      }
#pragma unroll
      for (int msk = 1; msk < 16; msk <<= 1)
        psum += __shfl_xor(psum, msk, 64);
      l_run[r] = l_run[r] * al[r] + psum;
    }
#pragma unroll
    for (int nj = 0; nj < 4; ++nj) {
      f32x4 o = o_acc[nj];
      o[0] *= al[0]; o[1] *= al[1]; o[2] *= al[2]; o[3] *= al[3];
      o_acc[nj] = o;
    }

    __syncthreads();   // cross-lane LDS handoff of P within each wave

    const int pa0 = (0 + lg) ^ (ll & 7);
    const int pa1 = (4 + lg) ^ (ll & 7);
    const bf16x8 ap0 = ldfrag(&sP[w][ll * 64 + pa0 * 8]);
    const bf16x8 ap1 = ldfrag(&sP[w][ll * 64 + pa1 * 8]);
#pragma unroll
    for (int nj = 0; nj < 4; ++nj) {
      const int row = nj * 16 + ll;    // dk row of sV
      const int p0 = (0 + lg) ^ (row & 7);
      const int p1 = (4 + lg) ^ (row & 7);
      o_acc[nj] = mfma16(ap0, ldfrag(&sV[row * 64 + p0 * 8]), o_acc[nj]);
      o_acc[nj] = mfma16(ap1, ldfrag(&sV[row * 64 + p1 * 8]), o_acc[nj]);
    }
  }

  const int b = bh >> 4, h = bh & 15;
#pragma unroll
  for (int r = 0; r < 4; ++r) {
    const float inv = 1.0f / l_run[r];
    const int srow = q0 + w * 16 + lg * 4 + r;
#pragma unroll
    for (int nj = 0; nj < 4; ++nj) {
      const int dk = nj * 16 + ll;
      ctx[((size_t)((b * S_LEN + srow) * NH + h)) * DKH + dk] =
          f2bf(o_acc[nj][r] * inv);
    }
  }
}

// ---------------- output projection GEMM ----------------
__global__ __launch_bounds__(256) void out_gemm(
    const u16* __restrict__ Am, const u16* __restrict__ W,
    const float* __restrict__ bo, float* __restrict__ out) {
  __shared__ __align__(16) u16 sA[128 * 32];
  __shared__ __align__(16) u16 sB[128 * 32];
  const int t = threadIdx.x;
  const int l = t & 63, w = t >> 6;
  const int ll = l & 15, lg = l >> 4;
  const int nb = blockIdx.x;  // 0..7
  const int mb = blockIdx.y;  // 0..31
  const int wr = (w >> 1) * 64, wc = (w & 1) * 64;

  f32x4 acc[4][4] = {};
  for (int kt = 0; kt < 32; ++kt) {
    const int k0 = kt * 32;
    __syncthreads();
#pragma unroll
    for (int i = 0; i < 2; ++i) {
      const int c = i * 256 + t;
      const int row = c >> 2;
      const int pc = c & 3;
      const int gc = pc ^ ((row ^ (row >> 2)) & 3);
      gl2lds16(Am + (size_t)(mb * 128 + row) * DEMB + k0 + gc * 8, &sA[c * 8]);
      gl2lds16(W + (size_t)(nb * 128 + row) * DEMB + k0 + gc * 8, &sB[c * 8]);
    }
    __syncthreads();
    bf16x8 af[4], bfr[4];
#pragma unroll
    for (int i2 = 0; i2 < 4; ++i2) {
      const int row = wr + i2 * 16 + ll;
      const int p = lg ^ ((row ^ (row >> 2)) & 3);
      af[i2] = ldfrag(&sA[row * 32 + p * 8]);
    }
#pragma unroll
    for (int j2 = 0; j2 < 4; ++j2) {
      const int row = wc + j2 * 16 + ll;
      const int p = lg ^ ((row ^ (row >> 2)) & 3);
      bfr[j2] = ldfrag(&sB[row * 32 + p * 8]);
    }
#pragma unroll
    for (int i2 = 0; i2 < 4; ++i2)
#pragma unroll
      for (int j2 = 0; j2 < 4; ++j2)
        acc[i2][j2] = mfma16(af[i2], bfr[j2], acc[i2][j2]);
  }

#pragma unroll
  for (int j2 = 0; j2 < 4; ++j2) {
    const int ncol = nb * 128 + wc + j2 * 16 + ll;
    const float bb = bo[ncol];
#pragma unroll
    for (int i2 = 0; i2 < 4; ++i2) {
#pragma unroll
      for (int r = 0; r < 4; ++r) {
        const int mrow = mb * 128 + wr + i2 * 16 + lg * 4 + r;
        out[(size_t)mrow * DEMB + ncol] = acc[i2][j2][r] + bb;
      }
    }
  }
}

extern "C" void kernel_launch(void* const* d_in, const int* in_sizes, int n_in,
                              void* d_out, int out_size, void* d_ws,
                              size_t ws_size, hipStream_t stream) {
  (void)in_sizes; (void)n_in; (void)out_size; (void)ws_size;
  const float* Q  = (const float*)d_in[0];
  const float* K  = (const float*)d_in[1];
  const float* V  = (const float*)d_in[2];
  const float* WQ = (const float*)d_in[3];
  const float* bQ = (const float*)d_in[4];
  const float* WK = (const float*)d_in[5];
  const float* bK = (const float*)d_in[6];
  const float* WV = (const float*)d_in[7];
  const float* bV = (const float*)d_in[8];
  const float* WO = (const float*)d_in[9];
  const float* bO = (const float*)d_in[10];
  float* out = (float*)d_out;

  // workspace layout (u16 elements); total 20,971,520 u16 = 40 MiB
  u16* ws   = (u16*)d_ws;
  u16* Wqkv = ws;                        // [3072,1024]
  u16* Wo   = Wqkv + 3072 * 1024;        // [1024,1024]
  u16* qh   = Wo + 1024 * 1024;          // [BH=32][S=2048][64]
  u16* kh   = qh + 32 * 2048 * 64;
  u16* vt   = kh + 32 * 2048 * 64;       // [BH][64][2048] (transposed)
  u16* ctx  = vt + 32 * 2048 * 64;       // [B][S][H][64] == [4096,1024]

  const int WN = DEMB * DEMB;            // 1,048,576
  cvt_bf16<<<WN / 1024, 256, 0, stream>>>(WQ, Wqkv, WN);
  cvt_bf16<<<WN / 1024, 256, 0, stream>>>(WK, Wqkv + WN, WN);
  cvt_bf16<<<WN / 1024, 256, 0, stream>>>(WV, Wqkv + 2 * WN, WN);
  cvt_bf16<<<WN / 1024, 256, 0, stream>>>(WO, Wo, WN);

  qkv_gemm<<<dim3(24, 32), 256, 0, stream>>>(Q, K, V, Wqkv, bQ, bK, bV,
                                             qh, kh, vt);
  attn_kernel<<<dim3(32, 32), 256, 0, stream>>>(qh, kh, vt, ctx);
  out_gemm<<<dim3(8, 32), 256, 0, stream>>>(ctx, Wo, bO, out);
}

// Round 2
// 281.460 us; speedup vs baseline: 1.2461x; 1.2461x over previous
//
#include <hip/hip_runtime.h>
#include <cstdint>
#include <cstddef>

// Problem constants: B=2, S=2048, D=1024, H=16, dk=64. M = B*S = 4096.
#define S_LEN 2048
#define NH    16
#define DKH   64
#define DEMB  1024
#define MTOT  4096

typedef float f32x4 __attribute__((ext_vector_type(4)));
typedef __bf16 bf16x8 __attribute__((ext_vector_type(8)));
typedef unsigned short u16;
typedef u16 u16x8 __attribute__((ext_vector_type(8)));
typedef u16 u16x4 __attribute__((ext_vector_type(4)));

static __device__ __forceinline__ u16 f2bf(float f) {
  unsigned int u = __builtin_bit_cast(unsigned int, f);
  u += 0x7fffu + ((u >> 16) & 1u);          // RNE
  return (u16)(u >> 16);
}
static __device__ __forceinline__ bf16x8 ldfrag(const u16* p) {
  return __builtin_bit_cast(bf16x8, *(const u16x8*)p);
}
static __device__ __forceinline__ f32x4 mfma16(bf16x8 a, bf16x8 b, f32x4 c) {
  return __builtin_amdgcn_mfma_f32_16x16x32_bf16(a, b, c, 0, 0, 0);
}
static __device__ __forceinline__ void gl2lds16(const void* g, void* l) {
  __builtin_amdgcn_global_load_lds((__attribute__((address_space(1))) void*)g,
                                   (__attribute__((address_space(3))) void*)l,
                                   16, 0, 0);
}

// 1/sqrt(dk) * log2(e): folded into the Q projection so attention scores are
// already in the exp2 domain.
#define SCL_Q (0.125f * 1.44269504088896340736f)

// ---------------- fp32 -> bf16 convert (weights) ----------------
__global__ __launch_bounds__(256) void cvt_bf16(const float* __restrict__ s,
                                                u16* __restrict__ d, int n) {
  int i = (blockIdx.x * 256 + threadIdx.x) * 4;
  if (i >= n) return;
  f32x4 f = *(const f32x4*)(s + i);
  u16x4 o;
  o[0] = f2bf(f[0]); o[1] = f2bf(f[1]); o[2] = f2bf(f[2]); o[3] = f2bf(f[3]);
  *(u16x4*)(d + i) = o;
}

// ---------------- fused QKV projection GEMM ----------------
// C[m,n] = A[m,:] . W[n,:] + bias[n].  A in {Q,K,V} selected per 1024-col
// segment. 128x128 tile, BK=32, 256 thr. Q output is pre-scaled by SCL_Q.
// V output goes through an LDS transpose -> coalesced [bh][dk][s] stores.
__global__ __launch_bounds__(256) void qkv_gemm(
    const float* __restrict__ Qm, const float* __restrict__ Km,
    const float* __restrict__ Vm, const u16* __restrict__ W,
    const float* __restrict__ bq, const float* __restrict__ bk,
    const float* __restrict__ bv,
    u16* __restrict__ qh, u16* __restrict__ kh, u16* __restrict__ vt) {
  __shared__ __align__(16) u16 sA[128 * 32];
  __shared__ __align__(16) u16 sB[128 * 32];
  __shared__ __align__(16) u16 sC[128 * 128];   // V-transpose staging
  const int t = threadIdx.x;
  const int l = t & 63, w = t >> 6;
  const int ll = l & 15, lg = l >> 4;
  const int nb = blockIdx.x;           // 0..23 (N = 3072)
  const int mb = blockIdx.y;           // 0..31 (M = 4096)
  const int which = nb >> 3;           // 0=Q,1=K,2=V
  const float* A = (which == 0) ? Qm : ((which == 1) ? Km : Vm);
  const int wr = (w >> 1) * 64, wc = (w & 1) * 64;

  f32x4 acc[4][4] = {};

  for (int kt = 0; kt < 32; ++kt) {
    const int k0 = kt * 32;
    __syncthreads();
#pragma unroll
    for (int i = 0; i < 2; ++i) {
      const int c = i * 256 + t;                 // physical 16B chunk 0..511
      const int row = c >> 2;                    // 0..127
      const int pc = c & 3;                      // physical col-chunk
      const int gc = pc ^ ((row ^ (row >> 2)) & 3);  // logical col-chunk
      const float* src = A + (size_t)(mb * 128 + row) * DEMB + k0 + gc * 8;
      f32x4 f0 = *(const f32x4*)src;
      f32x4 f1 = *(const f32x4*)(src + 4);
      u16x8 v;
      v[0] = f2bf(f0[0]); v[1] = f2bf(f0[1]); v[2] = f2bf(f0[2]); v[3] = f2bf(f0[3]);
      v[4] = f2bf(f1[0]); v[5] = f2bf(f1[1]); v[6] = f2bf(f1[2]); v[7] = f2bf(f1[3]);
      *(u16x8*)&sA[c * 8] = v;
      gl2lds16(W + (size_t)(nb * 128 + row) * DEMB + k0 + gc * 8, &sB[c * 8]);
    }
    __syncthreads();

    bf16x8 af[4], bfr[4];
#pragma unroll
    for (int i2 = 0; i2 < 4; ++i2) {
      const int row = wr + i2 * 16 + ll;
      const int p = lg ^ ((row ^ (row >> 2)) & 3);
      af[i2] = ldfrag(&sA[row * 32 + p * 8]);
    }
#pragma unroll
    for (int j2 = 0; j2 < 4; ++j2) {
      const int row = wc + j2 * 16 + ll;
      const int p = lg ^ ((row ^ (row >> 2)) & 3);
      bfr[j2] = ldfrag(&sB[row * 32 + p * 8]);
    }
#pragma unroll
    for (int i2 = 0; i2 < 4; ++i2)
#pragma unroll
      for (int j2 = 0; j2 < 4; ++j2)
        acc[i2][j2] = mfma16(af[i2], bfr[j2], acc[i2][j2]);
  }

  const float* bias = (which == 0) ? bq : ((which == 1) ? bk : bv);

  if (which == 2) {
    // ---- V: LDS transpose then coalesced [bh][dk][s] stores ----
#pragma unroll
    for (int j2 = 0; j2 < 4; ++j2) {
      const int dkl = wc + j2 * 16 + ll;          // local col 0..127
      const float bb = bias[(nb * 128 + dkl) & 1023];
#pragma unroll
      for (int i2 = 0; i2 < 4; ++i2) {
        const int sb = wr + i2 * 16 + lg * 4;     // local row base
        const int pch = (sb >> 2) ^ ((dkl & 7) * 4);  // swizzled 8B chunk
        u16x4 pk;
#pragma unroll
        for (int r = 0; r < 4; ++r) pk[r] = f2bf(acc[i2][j2][r] + bb);
        *(u16x4*)&sC[dkl * 128 + pch * 4] = pk;
      }
    }
    __syncthreads();
    const int s0g = (mb & 15) * 128;
    const int bidx = mb >> 4;
    const int h0 = (nb & 7) * 2;
#pragma unroll
    for (int i = 0; i < 8; ++i) {
      const int c16 = i * 256 + t;       // 0..2047
      const int dkl = c16 >> 4;
      const int sc = c16 & 15;
      const int pch = (sc * 2) ^ ((dkl & 7) * 4);
      const u16x8 val = *(const u16x8*)&sC[dkl * 128 + pch * 4];
      u16* dst = vt + ((size_t)((bidx * NH + h0 + (dkl >> 6)) * DKH + (dkl & 63))) * S_LEN
                 + s0g + sc * 8;
      *(u16x8*)dst = val;
    }
  } else {
    u16* outp = (which == 0) ? qh : kh;
    const float scl = (which == 0) ? SCL_Q : 1.0f;
#pragma unroll
    for (int j2 = 0; j2 < 4; ++j2) {
      const int ncol = nb * 128 + wc + j2 * 16 + ll;
      const int nl = ncol & 1023;
      const int h = nl >> 6, dk = nl & 63;
      const float bb = bias[nl];
#pragma unroll
      for (int i2 = 0; i2 < 4; ++i2) {
#pragma unroll
        for (int r = 0; r < 4; ++r) {
          const int mrow = mb * 128 + wr + i2 * 16 + lg * 4 + r;
          const int b = mrow >> 11, s = mrow & 2047;
          const float val = (acc[i2][j2][r] + bb) * scl;
          outp[((size_t)((b * NH + h) * S_LEN + s)) * DKH + dk] = f2bf(val);
        }
      }
    }
  }
}

// ---------------- flash attention (transposed formulation) ----------------
// One block = one (b,h) x 128 q-rows (wave w owns q rows w*32..w*32+31, as
// 2 q-tiles of 16). Key tile = 128. S^T = K.Q^T (A=K frag, B=Q frag),
// fixed-max softmax in exp2 domain (Q pre-scaled), P^T written per-wave to
// LDS as [q][key] (b64 writes), O^T = V^T.P^T (A=V^T frag, B=P^T frag).
// l = per-lane partial sum across the whole loop, 2 shuffles at the end.
__global__ __launch_bounds__(256) void attn_kernel(
    const u16* __restrict__ qh, const u16* __restrict__ kh,
    const u16* __restrict__ vt, u16* __restrict__ ctx) {
  __shared__ __align__(16) u16 sK[128 * 64];      // [key][dk]  16 KB
  __shared__ __align__(16) u16 sV[64 * 128];      // [dk][key]  16 KB
  __shared__ __align__(16) u16 sP[4][2][16 * 128];// per-wave/qt [q][key] 32 KB
  const int t = threadIdx.x;
  const int l = t & 63, w = t >> 6;
  const int ll = l & 15, lg = l >> 4;
  const int q_blk = blockIdx.x * 128;
  const int bh = blockIdx.y;

  // Q fragments (B-operand layout == A layout: q=ll, dk=f*32+lg*8..+7)
  bf16x8 aq[2][2];
#pragma unroll
  for (int qt = 0; qt < 2; ++qt) {
    const u16* qbase = qh + ((size_t)bh * S_LEN + q_blk + w * 32 + qt * 16 + ll) * DKH;
    aq[qt][0] = ldfrag(qbase + lg * 8);
    aq[qt][1] = ldfrag(qbase + 32 + lg * 8);
  }

  f32x4 oT[2][4] = {};        // [qt][dk-tile]; C layout: col=q=ll, row=dk
  float l_part[2] = {0.f, 0.f};

  u16* sP0 = &sP[w][0][0];
  u16* sP1 = &sP[w][1][0];

  for (int kt = 0; kt < 16; ++kt) {
    __syncthreads();
#pragma unroll
    for (int i = 0; i < 4; ++i) {
      const int c = i * 256 + t;                  // 16B chunk 0..1023
      {  // sK: 128 rows x 8 chunks, swizzle chunk ^ (row&7)
        const int row = c >> 3, gc = (c & 7) ^ (row & 7);
        gl2lds16(kh + ((size_t)bh * S_LEN + kt * 128 + row) * DKH + gc * 8,
                 &sK[c * 8]);
      }
      {  // sV: 64 rows x 16 chunks, swizzle chunk ^ (row&15)
        const int row = c >> 4, gc = (c & 15) ^ (row & 15);
        gl2lds16(vt + ((size_t)bh * DKH + row) * S_LEN + kt * 128 + gc * 8,
                 &sV[c * 8]);
      }
    }
    __syncthreads();

    // S^T and P^T, per 16-key block
#pragma unroll
    for (int kb = 0; kb < 8; ++kb) {
      const int krow = kb * 16 + ll;
      const bf16x8 ak0 = ldfrag(&sK[krow * 64 + (lg ^ (ll & 7)) * 8]);
      const bf16x8 ak1 = ldfrag(&sK[krow * 64 + ((4 + lg) ^ (ll & 7)) * 8]);
      f32x4 s0 = {}, s1 = {};
      s0 = mfma16(ak0, aq[0][0], s0);
      s0 = mfma16(ak1, aq[0][1], s0);
      s1 = mfma16(ak0, aq[1][0], s1);
      s1 = mfma16(ak1, aq[1][1], s1);
      const int poff = ll * 128 + ((kb ^ (ll & 7)) * 4 + lg) * 4;
      u16x4 pk;
      float ps = 0.f;
#pragma unroll
      for (int r = 0; r < 4; ++r) {
        const float p = __builtin_amdgcn_exp2f(s0[r]);
        ps += p; pk[r] = f2bf(p);
      }
      l_part[0] += ps;
      *(u16x4*)&sP0[poff] = pk;
      ps = 0.f;
#pragma unroll
      for (int r = 0; r < 4; ++r) {
        const float p = __builtin_amdgcn_exp2f(s1[r]);
        ps += p; pk[r] = f2bf(p);
      }
      l_part[1] += ps;
      *(u16x4*)&sP1[poff] = pk;
    }

    // O^T += V^T . P^T   (same-wave LDS ordering: DS ops complete in order)
    bf16x8 bp0[4], bp1[4];
#pragma unroll
    for (int f = 0; f < 4; ++f) {
      const int kb = f * 2 + (lg >> 1);
      const int off = ll * 128 + ((kb ^ (ll & 7)) * 4 + 2 * (lg & 1)) * 4;
      bp0[f] = ldfrag(&sP0[off]);
      bp1[f] = ldfrag(&sP1[off]);
    }
#pragma unroll
    for (int nt = 0; nt < 4; ++nt) {
      const int vrow = nt * 16 + ll;
#pragma unroll
      for (int f = 0; f < 4; ++f) {
        const bf16x8 av = ldfrag(&sV[vrow * 128 + ((f * 4 + lg) ^ ll) * 8]);
        oT[0][nt] = mfma16(av, bp0[f], oT[0][nt]);
        oT[1][nt] = mfma16(av, bp1[f], oT[1][nt]);
      }
    }
  }

  const int b = bh >> 4, h = bh & 15;
#pragma unroll
  for (int qt = 0; qt < 2; ++qt) {
    float lv = l_part[qt];
    lv += __shfl_xor(lv, 16, 64);
    lv += __shfl_xor(lv, 32, 64);
    const float inv = 1.0f / lv;
    const int srow = q_blk + w * 32 + qt * 16 + ll;
#pragma unroll
    for (int nt = 0; nt < 4; ++nt) {
      u16x4 o;
#pragma unroll
      for (int r = 0; r < 4; ++r) o[r] = f2bf(oT[qt][nt][r] * inv);
      *(u16x4*)&ctx[((size_t)((b * S_LEN + srow) * NH + h)) * DKH + nt * 16 + lg * 4] = o;
    }
  }
}

// ---------------- output projection GEMM ----------------
__global__ __launch_bounds__(256) void out_gemm(
    const u16* __restrict__ Am, const u16* __restrict__ W,
    const float* __restrict__ bo, float* __restrict__ out) {
  __shared__ __align__(16) u16 sA[128 * 32];
  __shared__ __align__(16) u16 sB[128 * 32];
  const int t = threadIdx.x;
  const int l = t & 63, w = t >> 6;
  const int ll = l & 15, lg = l >> 4;
  const int nb = blockIdx.x;  // 0..7
  const int mb = blockIdx.y;  // 0..31
  const int wr = (w >> 1) * 64, wc = (w & 1) * 64;

  f32x4 acc[4][4] = {};
  for (int kt = 0; kt < 32; ++kt) {
    const int k0 = kt * 32;
    __syncthreads();
#pragma unroll
    for (int i = 0; i < 2; ++i) {
      const int c = i * 256 + t;
      const int row = c >> 2;
      const int pc = c & 3;
      const int gc = pc ^ ((row ^ (row >> 2)) & 3);
      gl2lds16(Am + (size_t)(mb * 128 + row) * DEMB + k0 + gc * 8, &sA[c * 8]);
      gl2lds16(W + (size_t)(nb * 128 + row) * DEMB + k0 + gc * 8, &sB[c * 8]);
    }
    __syncthreads();
    bf16x8 af[4], bfr[4];
#pragma unroll
    for (int i2 = 0; i2 < 4; ++i2) {
      const int row = wr + i2 * 16 + ll;
      const int p = lg ^ ((row ^ (row >> 2)) & 3);
      af[i2] = ldfrag(&sA[row * 32 + p * 8]);
    }
#pragma unroll
    for (int j2 = 0; j2 < 4; ++j2) {
      const int row = wc + j2 * 16 + ll;
      const int p = lg ^ ((row ^ (row >> 2)) & 3);
      bfr[j2] = ldfrag(&sB[row * 32 + p * 8]);
    }
#pragma unroll
    for (int i2 = 0; i2 < 4; ++i2)
#pragma unroll
      for (int j2 = 0; j2 < 4; ++j2)
        acc[i2][j2] = mfma16(af[i2], bfr[j2], acc[i2][j2]);
  }

#pragma unroll
  for (int j2 = 0; j2 < 4; ++j2) {
    const int ncol = nb * 128 + wc + j2 * 16 + ll;
    const float bb = bo[ncol];
#pragma unroll
    for (int i2 = 0; i2 < 4; ++i2) {
#pragma unroll
      for (int r = 0; r < 4; ++r) {
        const int mrow = mb * 128 + wr + i2 * 16 + lg * 4 + r;
        out[(size_t)mrow * DEMB + ncol] = acc[i2][j2][r] + bb;
      }
    }
  }
}

extern "C" void kernel_launch(void* const* d_in, const int* in_sizes, int n_in,
                              void* d_out, int out_size, void* d_ws,
                              size_t ws_size, hipStream_t stream) {
  (void)in_sizes; (void)n_in; (void)out_size; (void)ws_size;
  const float* Q  = (const float*)d_in[0];
  const float* K  = (const float*)d_in[1];
  const float* V  = (const float*)d_in[2];
  const float* WQ = (const float*)d_in[3];
  const float* bQ = (const float*)d_in[4];
  const float* WK = (const float*)d_in[5];
  const float* bK = (const float*)d_in[6];
  const float* WV = (const float*)d_in[7];
  const float* bV = (const float*)d_in[8];
  const float* WO = (const float*)d_in[9];
  const float* bO = (const float*)d_in[10];
  float* out = (float*)d_out;

  u16* ws   = (u16*)d_ws;
  u16* Wqkv = ws;                        // [3072,1024]
  u16* Wo   = Wqkv + 3072 * 1024;        // [1024,1024]
  u16* qh   = Wo + 1024 * 1024;          // [BH=32][S=2048][64] (pre-scaled)
  u16* kh   = qh + 32 * 2048 * 64;
  u16* vt   = kh + 32 * 2048 * 64;       // [BH][64][2048] (transposed)
  u16* ctx  = vt + 32 * 2048 * 64;       // [B][S][H][64] == [4096,1024]

  const int WN = DEMB * DEMB;
  cvt_bf16<<<WN / 1024, 256, 0, stream>>>(WQ, Wqkv, WN);
  cvt_bf16<<<WN / 1024, 256, 0, stream>>>(WK, Wqkv + WN, WN);
  cvt_bf16<<<WN / 1024, 256, 0, stream>>>(WV, Wqkv + 2 * WN, WN);
  cvt_bf16<<<WN / 1024, 256, 0, stream>>>(WO, Wo, WN);

  qkv_gemm<<<dim3(24, 32), 256, 0, stream>>>(Q, K, V, Wqkv, bQ, bK, bV,
                                             qh, kh, vt);
  attn_kernel<<<dim3(16, 32), 256, 0, stream>>>(qh, kh, vt, ctx);
  out_gemm<<<dim3(8, 32), 256, 0, stream>>>(ctx, Wo, bO, out);
}

// Round 3
// 265.799 us; speedup vs baseline: 1.3196x; 1.0589x over previous
//
#include <hip/hip_runtime.h>
#include <cstdint>
#include <cstddef>

// Problem constants: B=2, S=2048, D=1024, H=16, dk=64. M = B*S = 4096.
#define S_LEN 2048
#define NH    16
#define DKH   64
#define DEMB  1024
#define MTOT  4096

typedef float f32x4 __attribute__((ext_vector_type(4)));
typedef __bf16 bf16x8 __attribute__((ext_vector_type(8)));
typedef unsigned short u16;
typedef unsigned int u32;
typedef u16 u16x8 __attribute__((ext_vector_type(8)));
typedef u16 u16x4 __attribute__((ext_vector_type(4)));
typedef u32 u32x4 __attribute__((ext_vector_type(4)));

static __device__ __forceinline__ u16 f2bf(float f) {
  u32 u = __builtin_bit_cast(u32, f);
  u += 0x7fffu + ((u >> 16) & 1u);          // RNE
  return (u16)(u >> 16);
}
static __device__ __forceinline__ bf16x8 ldfrag(const u16* p) {
  return __builtin_bit_cast(bf16x8, *(const u16x8*)p);
}
static __device__ __forceinline__ f32x4 mfma16(bf16x8 a, bf16x8 b, f32x4 c) {
  return __builtin_amdgcn_mfma_f32_16x16x32_bf16(a, b, c, 0, 0, 0);
}
static __device__ __forceinline__ void gl2lds16(const void* g, void* l) {
  __builtin_amdgcn_global_load_lds((__attribute__((address_space(1))) void*)g,
                                   (__attribute__((address_space(3))) void*)l,
                                   16, 0, 0);
}
// pack two fp32 -> two bf16 (round-half-up) in one v_perm
static __device__ __forceinline__ u32 pkbf(float hi, float lo) {
  u32 a = __builtin_bit_cast(u32, hi) + 0x8000u;
  u32 b = __builtin_bit_cast(u32, lo) + 0x8000u;
  return __builtin_amdgcn_perm(a, b, 0x07060302u);
}
static __device__ __forceinline__ bf16x8 cvt8(f32x4 a, f32x4 b) {
  u32x4 r;
  r[0] = pkbf(a[1], a[0]); r[1] = pkbf(a[3], a[2]);
  r[2] = pkbf(b[1], b[0]); r[3] = pkbf(b[3], b[2]);
  return __builtin_bit_cast(bf16x8, r);
}

// 1/sqrt(dk) * log2(e): folded into the Q projection so attention scores are
// already in the exp2 domain.
#define SCL_Q (0.125f * 1.44269504088896340736f)

// ---------------- fp32 -> bf16 convert (weights) ----------------
__global__ __launch_bounds__(256) void cvt_bf16(const float* __restrict__ s,
                                                u16* __restrict__ d, int n) {
  int i = (blockIdx.x * 256 + threadIdx.x) * 4;
  if (i >= n) return;
  f32x4 f = *(const f32x4*)(s + i);
  u16x4 o;
  o[0] = f2bf(f[0]); o[1] = f2bf(f[1]); o[2] = f2bf(f[2]); o[3] = f2bf(f[3]);
  *(u16x4*)(d + i) = o;
}

// ---------------- fused QKV projection GEMM ----------------
// C[m,n] = A[m,:] . W[n,:] + bias[n].  A in {Q,K,V} per 1024-col segment.
// 128x128 tile, BK=32, 256 thr. A staged as *fp32* via global_load_lds
// (fully async), converted to bf16 at frag-read time. W staged bf16 async.
// Q output pre-scaled by SCL_Q; V output scatter-stored transposed
// [bh][dk][s] directly from registers (u16x4 per 4 consecutive s).
__global__ __launch_bounds__(256) void qkv_gemm(
    const float* __restrict__ Qm, const float* __restrict__ Km,
    const float* __restrict__ Vm, const u16* __restrict__ W,
    const float* __restrict__ bq, const float* __restrict__ bk,
    const float* __restrict__ bv,
    u16* __restrict__ qh, u16* __restrict__ kh, u16* __restrict__ vt) {
  __shared__ __align__(16) float sAf[128 * 32];   // 16 KB fp32 A tile
  __shared__ __align__(16) u16   sB[128 * 32];    // 8 KB bf16 W tile
  const int t = threadIdx.x;
  const int l = t & 63, w = t >> 6;
  const int ll = l & 15, lg = l >> 4;
  const int nb = blockIdx.x;           // 0..23 (N = 3072)
  const int mb = blockIdx.y;           // 0..31 (M = 4096)
  const int which = nb >> 3;           // 0=Q,1=K,2=V
  const float* A = (which == 0) ? Qm : ((which == 1) ? Km : Vm);
  const int wr = (w >> 1) * 64, wc = (w & 1) * 64;

  f32x4 acc[4][4] = {};

  for (int kt = 0; kt < 32; ++kt) {
    const int k0 = kt * 32;
    __syncthreads();
    // A: 128 rows x 32 fp32 = 1024 16B chunks; 32B granule XOR swizzle
#pragma unroll
    for (int i = 0; i < 4; ++i) {
      const int c = i * 256 + t;
      const int row = c >> 3;
      const int gp = (c >> 1) & 3;               // physical 32B granule
      const int half = c & 1;
      const int gl = gp ^ (row & 3);             // logical granule
      gl2lds16(A + (size_t)(mb * 128 + row) * DEMB + k0 + gl * 8 + half * 4,
               &sAf[c * 4]);
    }
    // W: 128 rows x 32 bf16 = 512 16B chunks; 16B chunk XOR swizzle
#pragma unroll
    for (int i = 0; i < 2; ++i) {
      const int c = i * 256 + t;
      const int row = c >> 2;
      const int gc = (c & 3) ^ (row & 3);
      gl2lds16(W + (size_t)(nb * 128 + row) * DEMB + k0 + gc * 8, &sB[c * 8]);
    }
    __syncthreads();

    bf16x8 af[4], bfr[4];
#pragma unroll
    for (int i2 = 0; i2 < 4; ++i2) {
      const int row = wr + i2 * 16 + ll;
      const float* p = &sAf[row * 32 + (lg ^ (row & 3)) * 8];
      f32x4 f0 = *(const f32x4*)p;
      f32x4 f1 = *(const f32x4*)(p + 4);
      af[i2] = cvt8(f0, f1);
    }
#pragma unroll
    for (int j2 = 0; j2 < 4; ++j2) {
      const int row = wc + j2 * 16 + ll;
      bfr[j2] = ldfrag(&sB[row * 32 + (lg ^ (row & 3)) * 8]);
    }
#pragma unroll
    for (int i2 = 0; i2 < 4; ++i2)
#pragma unroll
      for (int j2 = 0; j2 < 4; ++j2)
        acc[i2][j2] = mfma16(af[i2], bfr[j2], acc[i2][j2]);
  }

  const float* bias = (which == 0) ? bq : ((which == 1) ? bk : bv);
  const int b = (mb * 128) >> 11;                // tile never crosses batch

  if (which == 2) {
    // V: register scatter to [bh][dk][s]; 4 consecutive s per u16x4 store
#pragma unroll
    for (int j2 = 0; j2 < 4; ++j2) {
      const int nl = (nb * 128 + wc + j2 * 16 + ll) & 1023;
      const int h = nl >> 6, dk = nl & 63;
      const float bb = bias[nl];
      u16* base = vt + ((size_t)((b * NH + h) * DKH + dk)) * S_LEN;
#pragma unroll
      for (int i2 = 0; i2 < 4; ++i2) {
        const int s = (mb * 128 + wr + i2 * 16 + lg * 4) & 2047;
        u16x4 pk;
#pragma unroll
        for (int r = 0; r < 4; ++r) pk[r] = f2bf(acc[i2][j2][r] + bb);
        *(u16x4*)&base[s] = pk;
      }
    }
  } else {
    u16* outp = (which == 0) ? qh : kh;
    const float scl = (which == 0) ? SCL_Q : 1.0f;
#pragma unroll
    for (int j2 = 0; j2 < 4; ++j2) {
      const int nl = (nb * 128 + wc + j2 * 16 + ll) & 1023;
      const int h = nl >> 6, dk = nl & 63;
      const float bb = bias[nl];
#pragma unroll
      for (int i2 = 0; i2 < 4; ++i2) {
#pragma unroll
        for (int r = 0; r < 4; ++r) {
          const int s = (mb * 128 + wr + i2 * 16 + lg * 4 + r) & 2047;
          const float val = (acc[i2][j2][r] + bb) * scl;
          outp[((size_t)((b * NH + h) * S_LEN + s)) * DKH + dk] = f2bf(val);
        }
      }
    }
  }
}

// ---------------- flash attention (transposed formulation) ----------------
// One block = one (b,h) x 128 q-rows (wave w owns q rows w*32..w*32+31, as
// 2 q-tiles of 16). Key tile = 128. S^T = K.Q^T (A=K frag, B=Q frag),
// fixed-max softmax in exp2 domain (Q pre-scaled), P^T written per-wave to
// LDS as [q][key] (b64 writes), O^T = V^T.P^T (A=V^T frag, B=P^T frag).
// l = per-lane partial sum across the whole loop, 2 shuffles at the end.
__global__ __launch_bounds__(256) void attn_kernel(
    const u16* __restrict__ qh, const u16* __restrict__ kh,
    const u16* __restrict__ vt, u16* __restrict__ ctx) {
  __shared__ __align__(16) u16 sK[128 * 64];      // [key][dk]  16 KB
  __shared__ __align__(16) u16 sV[64 * 128];      // [dk][key]  16 KB
  __shared__ __align__(16) u16 sP[4][2][16 * 128];// per-wave/qt [q][key] 32 KB
  const int t = threadIdx.x;
  const int l = t & 63, w = t >> 6;
  const int ll = l & 15, lg = l >> 4;
  const int q_blk = blockIdx.x * 128;
  const int bh = blockIdx.y;

  // Q fragments (B-operand layout == A layout: q=ll, dk=f*32+lg*8..+7)
  bf16x8 aq[2][2];
#pragma unroll
  for (int qt = 0; qt < 2; ++qt) {
    const u16* qbase = qh + ((size_t)bh * S_LEN + q_blk + w * 32 + qt * 16 + ll) * DKH;
    aq[qt][0] = ldfrag(qbase + lg * 8);
    aq[qt][1] = ldfrag(qbase + 32 + lg * 8);
  }

  f32x4 oT[2][4] = {};        // [qt][dk-tile]; C layout: col=q=ll, row=dk
  float l_part[2] = {0.f, 0.f};

  u16* sP0 = &sP[w][0][0];
  u16* sP1 = &sP[w][1][0];

  for (int kt = 0; kt < 16; ++kt) {
    __syncthreads();
#pragma unroll
    for (int i = 0; i < 4; ++i) {
      const int c = i * 256 + t;                  // 16B chunk 0..1023
      {  // sK: 128 rows x 8 chunks, swizzle chunk ^ (row&7)
        const int row = c >> 3, gc = (c & 7) ^ (row & 7);
        gl2lds16(kh + ((size_t)bh * S_LEN + kt * 128 + row) * DKH + gc * 8,
                 &sK[c * 8]);
      }
      {  // sV: 64 rows x 16 chunks, swizzle chunk ^ (row&15)
        const int row = c >> 4, gc = (c & 15) ^ (row & 15);
        gl2lds16(vt + ((size_t)bh * DKH + row) * S_LEN + kt * 128 + gc * 8,
                 &sV[c * 8]);
      }
    }
    __syncthreads();

    // S^T and P^T, per 16-key block
#pragma unroll
    for (int kb = 0; kb < 8; ++kb) {
      const int krow = kb * 16 + ll;
      const bf16x8 ak0 = ldfrag(&sK[krow * 64 + (lg ^ (ll & 7)) * 8]);
      const bf16x8 ak1 = ldfrag(&sK[krow * 64 + ((4 + lg) ^ (ll & 7)) * 8]);
      f32x4 s0 = {}, s1 = {};
      s0 = mfma16(ak0, aq[0][0], s0);
      s0 = mfma16(ak1, aq[0][1], s0);
      s1 = mfma16(ak0, aq[1][0], s1);
      s1 = mfma16(ak1, aq[1][1], s1);
      const int poff = ll * 128 + ((kb ^ (ll & 7)) * 4 + lg) * 4;
      u16x4 pk;
      float ps = 0.f;
#pragma unroll
      for (int r = 0; r < 4; ++r) {
        const float p = __builtin_amdgcn_exp2f(s0[r]);
        ps += p; pk[r] = f2bf(p);
      }
      l_part[0] += ps;
      *(u16x4*)&sP0[poff] = pk;
      ps = 0.f;
#pragma unroll
      for (int r = 0; r < 4; ++r) {
        const float p = __builtin_amdgcn_exp2f(s1[r]);
        ps += p; pk[r] = f2bf(p);
      }
      l_part[1] += ps;
      *(u16x4*)&sP1[poff] = pk;
    }

    // O^T += V^T . P^T   (same-wave LDS ordering: DS ops complete in order)
    bf16x8 bp0[4], bp1[4];
#pragma unroll
    for (int f = 0; f < 4; ++f) {
      const int kb = f * 2 + (lg >> 1);
      const int off = ll * 128 + ((kb ^ (ll & 7)) * 4 + 2 * (lg & 1)) * 4;
      bp0[f] = ldfrag(&sP0[off]);
      bp1[f] = ldfrag(&sP1[off]);
    }
#pragma unroll
    for (int nt = 0; nt < 4; ++nt) {
      const int vrow = nt * 16 + ll;
#pragma unroll
      for (int f = 0; f < 4; ++f) {
        const bf16x8 av = ldfrag(&sV[vrow * 128 + ((f * 4 + lg) ^ ll) * 8]);
        oT[0][nt] = mfma16(av, bp0[f], oT[0][nt]);
        oT[1][nt] = mfma16(av, bp1[f], oT[1][nt]);
      }
    }
  }

  const int b = bh >> 4, h = bh & 15;
#pragma unroll
  for (int qt = 0; qt < 2; ++qt) {
    float lv = l_part[qt];
    lv += __shfl_xor(lv, 16, 64);
    lv += __shfl_xor(lv, 32, 64);
    const float inv = 1.0f / lv;
    const int srow = q_blk + w * 32 + qt * 16 + ll;
#pragma unroll
    for (int nt = 0; nt < 4; ++nt) {
      u16x4 o;
#pragma unroll
      for (int r = 0; r < 4; ++r) o[r] = f2bf(oT[qt][nt][r] * inv);
      *(u16x4*)&ctx[((size_t)((b * S_LEN + srow) * NH + h)) * DKH + nt * 16 + lg * 4] = o;
    }
  }
}

// ---------------- output projection GEMM ----------------
// 64x64 tile, BK=64, 4 waves (2x2 of 32x32). Grid (16,64) = 1024 blocks
// = 4 blocks/CU -> ~16 waves/CU for latency hiding (the 128^2 version was
// 256 blocks = 1 block/CU, latency-bound).
__global__ __launch_bounds__(256) void out_gemm(
    const u16* __restrict__ Am, const u16* __restrict__ W,
    const float* __restrict__ bo, float* __restrict__ out) {
  __shared__ __align__(16) u16 sA[64 * 64];   // 8 KB
  __shared__ __align__(16) u16 sB[64 * 64];   // 8 KB
  const int t = threadIdx.x;
  const int l = t & 63, w = t >> 6;
  const int ll = l & 15, lg = l >> 4;
  const int nb = blockIdx.x;  // 0..15
  const int mb = blockIdx.y;  // 0..63
  const int wr = (w >> 1) * 32, wc = (w & 1) * 32;

  f32x4 acc[2][2] = {};
  for (int kt = 0; kt < 16; ++kt) {
    const int k0 = kt * 64;
    __syncthreads();
#pragma unroll
    for (int i = 0; i < 2; ++i) {
      const int c = i * 256 + t;               // 512 chunks per buffer
      const int row = c >> 3;
      const int gc = (c & 7) ^ (row & 7);
      gl2lds16(Am + (size_t)(mb * 64 + row) * DEMB + k0 + gc * 8, &sA[c * 8]);
      gl2lds16(W + (size_t)(nb * 64 + row) * DEMB + k0 + gc * 8, &sB[c * 8]);
    }
    __syncthreads();
#pragma unroll
    for (int sub = 0; sub < 2; ++sub) {
      bf16x8 af[2], bfr[2];
#pragma unroll
      for (int i2 = 0; i2 < 2; ++i2) {
        const int row = wr + i2 * 16 + ll;
        af[i2] = ldfrag(&sA[row * 64 + ((sub * 4 + lg) ^ (row & 7)) * 8]);
      }
#pragma unroll
      for (int j2 = 0; j2 < 2; ++j2) {
        const int row = wc + j2 * 16 + ll;
        bfr[j2] = ldfrag(&sB[row * 64 + ((sub * 4 + lg) ^ (row & 7)) * 8]);
      }
#pragma unroll
      for (int i2 = 0; i2 < 2; ++i2)
#pragma unroll
        for (int j2 = 0; j2 < 2; ++j2)
          acc[i2][j2] = mfma16(af[i2], bfr[j2], acc[i2][j2]);
    }
  }

#pragma unroll
  for (int j2 = 0; j2 < 2; ++j2) {
    const int ncol = nb * 64 + wc + j2 * 16 + ll;
    const float bb = bo[ncol];
#pragma unroll
    for (int i2 = 0; i2 < 2; ++i2) {
#pragma unroll
      for (int r = 0; r < 4; ++r) {
        const int mrow = mb * 64 + wr + i2 * 16 + lg * 4 + r;
        out[(size_t)mrow * DEMB + ncol] = acc[i2][j2][r] + bb;
      }
    }
  }
}

extern "C" void kernel_launch(void* const* d_in, const int* in_sizes, int n_in,
                              void* d_out, int out_size, void* d_ws,
                              size_t ws_size, hipStream_t stream) {
  (void)in_sizes; (void)n_in; (void)out_size; (void)ws_size;
  const float* Q  = (const float*)d_in[0];
  const float* K  = (const float*)d_in[1];
  const float* V  = (const float*)d_in[2];
  const float* WQ = (const float*)d_in[3];
  const float* bQ = (const float*)d_in[4];
  const float* WK = (const float*)d_in[5];
  const float* bK = (const float*)d_in[6];
  const float* WV = (const float*)d_in[7];
  const float* bV = (const float*)d_in[8];
  const float* WO = (const float*)d_in[9];
  const float* bO = (const float*)d_in[10];
  float* out = (float*)d_out;

  // workspace (u16 units): 3M + 1M + 4M + 4M + 4M + 4M = 20M u16 = 40 MiB
  u16* ws   = (u16*)d_ws;
  u16* Wqkv = ws;                        // [3072,1024]
  u16* Wo   = Wqkv + 3072 * 1024;        // [1024,1024]
  u16* qh   = Wo + 1024 * 1024;          // [BH=32][S=2048][64] (pre-scaled)
  u16* kh   = qh + 32 * 2048 * 64;       // [BH][S][64]
  u16* vt   = kh + 32 * 2048 * 64;       // [BH][64][S] (transposed)
  u16* ctx  = vt + 32 * 2048 * 64;       // [B][S][H][64] == [4096,1024]

  const int WN = DEMB * DEMB;
  cvt_bf16<<<WN / 1024, 256, 0, stream>>>(WQ, Wqkv, WN);
  cvt_bf16<<<WN / 1024, 256, 0, stream>>>(WK, Wqkv + WN, WN);
  cvt_bf16<<<WN / 1024, 256, 0, stream>>>(WV, Wqkv + 2 * WN, WN);
  cvt_bf16<<<WN / 1024, 256, 0, stream>>>(WO, Wo, WN);

  qkv_gemm<<<dim3(24, 32), 256, 0, stream>>>(Q, K, V, Wqkv, bQ, bK, bV,
                                             qh, kh, vt);
  attn_kernel<<<dim3(16, 32), 256, 0, stream>>>(qh, kh, vt, ctx);
  out_gemm<<<dim3(16, 64), 256, 0, stream>>>(ctx, Wo, bO, out);
}

// Round 4
// 257.052 us; speedup vs baseline: 1.3645x; 1.0340x over previous
//
#include <hip/hip_runtime.h>
#include <cstdint>
#include <cstddef>

// Problem constants: B=2, S=2048, D=1024, H=16, dk=64. M = B*S = 4096.
#define S_LEN 2048
#define NH    16
#define DKH   64
#define DEMB  1024
#define MTOT  4096

typedef float f32x4 __attribute__((ext_vector_type(4)));
typedef __bf16 bf16x8 __attribute__((ext_vector_type(8)));
typedef unsigned short u16;
typedef unsigned int u32;
typedef u16 u16x8 __attribute__((ext_vector_type(8)));
typedef u16 u16x4 __attribute__((ext_vector_type(4)));

static __device__ __forceinline__ u16 f2bf(float f) {
  u32 u = __builtin_bit_cast(u32, f);
  u += 0x7fffu + ((u >> 16) & 1u);          // RNE
  return (u16)(u >> 16);
}
static __device__ __forceinline__ bf16x8 ldfrag(const u16* p) {
  return __builtin_bit_cast(bf16x8, *(const u16x8*)p);
}
static __device__ __forceinline__ f32x4 mfma16(bf16x8 a, bf16x8 b, f32x4 c) {
  return __builtin_amdgcn_mfma_f32_16x16x32_bf16(a, b, c, 0, 0, 0);
}
static __device__ __forceinline__ void gl2lds16(const void* g, void* l) {
  __builtin_amdgcn_global_load_lds((__attribute__((address_space(1))) void*)g,
                                   (__attribute__((address_space(3))) void*)l,
                                   16, 0, 0);
}

// 1/sqrt(dk) * log2(e): folded into the Q projection so attention scores are
// already in the exp2 domain.
#define SCL_Q (0.125f * 1.44269504088896340736f)

// ---------------- fp32 -> bf16 convert (weights + activations) ----------------
__global__ __launch_bounds__(256) void cvt_bf16(const float* __restrict__ s,
                                                u16* __restrict__ d, int n) {
  int i = (blockIdx.x * 256 + threadIdx.x) * 4;
  if (i >= n) return;
  f32x4 f = *(const f32x4*)(s + i);
  u16x4 o;
  o[0] = f2bf(f[0]); o[1] = f2bf(f[1]); o[2] = f2bf(f[2]); o[3] = f2bf(f[3]);
  *(u16x4*)(d + i) = o;
}

// ---------------- fused QKV projection GEMM (pure bf16, m97 structure) -------
// C[m,n] = A[m,:] . W[n,:] + bias[n].  A in {qin,kin,vin} per 1024-col
// segment (pre-converted bf16). 128x128 tile, BK=32, 256 thr, both operands
// via global_load_lds width=16 (2 chunks/thread each). LDS swizzle:
// physical chunk pc of row holds global chunk pc ^ ((row>>1)&3) -> frag
// reads are exactly 2-way bank-aliased (free, m136).
// Q output pre-scaled by SCL_Q; V output scatter-stored transposed
// [bh][dk][s] directly from registers (u16x4 per 4 consecutive s).
__global__ __launch_bounds__(256) void qkv_gemm(
    const u16* __restrict__ qin, const u16* __restrict__ kin,
    const u16* __restrict__ vin, const u16* __restrict__ W,
    const float* __restrict__ bq, const float* __restrict__ bk,
    const float* __restrict__ bv,
    u16* __restrict__ qh, u16* __restrict__ kh, u16* __restrict__ vt) {
  __shared__ __align__(16) u16 sA[128 * 32];    // 8 KB
  __shared__ __align__(16) u16 sB[128 * 32];    // 8 KB
  const int t = threadIdx.x;
  const int l = t & 63, w = t >> 6;
  const int ll = l & 15, lg = l >> 4;
  const int nb = blockIdx.x;           // 0..23 (N = 3072)
  const int mb = blockIdx.y;           // 0..31 (M = 4096)
  const int which = nb >> 3;           // 0=Q,1=K,2=V
  const u16* A = (which == 0) ? qin : ((which == 1) ? kin : vin);
  const int wr = (w >> 1) * 64, wc = (w & 1) * 64;

  f32x4 acc[4][4] = {};

  for (int kt = 0; kt < 32; ++kt) {
    const int k0 = kt * 32;
    __syncthreads();
#pragma unroll
    for (int i = 0; i < 2; ++i) {
      const int c = i * 256 + t;                 // 16B chunk 0..511
      const int row = c >> 2;                    // 0..127
      const int gc = (c & 3) ^ ((row >> 1) & 3); // global col-chunk
      gl2lds16(A + (size_t)(mb * 128 + row) * DEMB + k0 + gc * 8, &sA[c * 8]);
      gl2lds16(W + (size_t)(nb * 128 + row) * DEMB + k0 + gc * 8, &sB[c * 8]);
    }
    __syncthreads();

    bf16x8 af[4], bfr[4];
#pragma unroll
    for (int i2 = 0; i2 < 4; ++i2) {
      const int row = wr + i2 * 16 + ll;
      af[i2] = ldfrag(&sA[row * 32 + (lg ^ ((row >> 1) & 3)) * 8]);
    }
#pragma unroll
    for (int j2 = 0; j2 < 4; ++j2) {
      const int row = wc + j2 * 16 + ll;
      bfr[j2] = ldfrag(&sB[row * 32 + (lg ^ ((row >> 1) & 3)) * 8]);
    }
#pragma unroll
    for (int i2 = 0; i2 < 4; ++i2)
#pragma unroll
      for (int j2 = 0; j2 < 4; ++j2)
        acc[i2][j2] = mfma16(af[i2], bfr[j2], acc[i2][j2]);
  }

  const float* bias = (which == 0) ? bq : ((which == 1) ? bk : bv);
  const int b = (mb * 128) >> 11;                // tile never crosses batch

  if (which == 2) {
    // V: register scatter to [bh][dk][s]; 4 consecutive s per u16x4 store
#pragma unroll
    for (int j2 = 0; j2 < 4; ++j2) {
      const int nl = (nb * 128 + wc + j2 * 16 + ll) & 1023;
      const int h = nl >> 6, dk = nl & 63;
      const float bb = bias[nl];
      u16* base = vt + ((size_t)((b * NH + h) * DKH + dk)) * S_LEN;
#pragma unroll
      for (int i2 = 0; i2 < 4; ++i2) {
        const int s = (mb * 128 + wr + i2 * 16 + lg * 4) & 2047;
        u16x4 pk;
#pragma unroll
        for (int r = 0; r < 4; ++r) pk[r] = f2bf(acc[i2][j2][r] + bb);
        *(u16x4*)&base[s] = pk;
      }
    }
  } else {
    u16* outp = (which == 0) ? qh : kh;
    const float scl = (which == 0) ? SCL_Q : 1.0f;
#pragma unroll
    for (int j2 = 0; j2 < 4; ++j2) {
      const int nl = (nb * 128 + wc + j2 * 16 + ll) & 1023;
      const int h = nl >> 6, dk = nl & 63;
      const float bb = bias[nl];
#pragma unroll
      for (int i2 = 0; i2 < 4; ++i2) {
#pragma unroll
        for (int r = 0; r < 4; ++r) {
          const int s = (mb * 128 + wr + i2 * 16 + lg * 4 + r) & 2047;
          const float val = (acc[i2][j2][r] + bb) * scl;
          outp[((size_t)((b * NH + h) * S_LEN + s)) * DKH + dk] = f2bf(val);
        }
      }
    }
  }
}

// ---------------- flash attention (transposed formulation) ----------------
// One block = one (b,h) x 128 q-rows (wave w owns q rows w*32..w*32+31, as
// 2 q-tiles of 16). Key tile = 128. S^T = K.Q^T (A=K frag, B=Q frag),
// fixed-max softmax in exp2 domain (Q pre-scaled), P^T written per-wave to
// LDS as [q][key] (b64 writes), O^T = V^T.P^T (A=V^T frag, B=P^T frag).
// l = per-lane partial sum across the whole loop, 2 shuffles at the end.
__global__ __launch_bounds__(256) void attn_kernel(
    const u16* __restrict__ qh, const u16* __restrict__ kh,
    const u16* __restrict__ vt, u16* __restrict__ ctx) {
  __shared__ __align__(16) u16 sK[128 * 64];      // [key][dk]  16 KB
  __shared__ __align__(16) u16 sV[64 * 128];      // [dk][key]  16 KB
  __shared__ __align__(16) u16 sP[4][2][16 * 128];// per-wave/qt [q][key] 32 KB
  const int t = threadIdx.x;
  const int l = t & 63, w = t >> 6;
  const int ll = l & 15, lg = l >> 4;
  const int q_blk = blockIdx.x * 128;
  const int bh = blockIdx.y;

  // Q fragments (B-operand layout == A layout: q=ll, dk=f*32+lg*8..+7)
  bf16x8 aq[2][2];
#pragma unroll
  for (int qt = 0; qt < 2; ++qt) {
    const u16* qbase = qh + ((size_t)bh * S_LEN + q_blk + w * 32 + qt * 16 + ll) * DKH;
    aq[qt][0] = ldfrag(qbase + lg * 8);
    aq[qt][1] = ldfrag(qbase + 32 + lg * 8);
  }

  f32x4 oT[2][4] = {};        // [qt][dk-tile]; C layout: col=q=ll, row=dk
  float l_part[2] = {0.f, 0.f};

  u16* sP0 = &sP[w][0][0];
  u16* sP1 = &sP[w][1][0];

  for (int kt = 0; kt < 16; ++kt) {
    __syncthreads();
#pragma unroll
    for (int i = 0; i < 4; ++i) {
      const int c = i * 256 + t;                  // 16B chunk 0..1023
      {  // sK: 128 rows x 8 chunks, swizzle chunk ^ (row&7)
        const int row = c >> 3, gc = (c & 7) ^ (row & 7);
        gl2lds16(kh + ((size_t)bh * S_LEN + kt * 128 + row) * DKH + gc * 8,
                 &sK[c * 8]);
      }
      {  // sV: 64 rows x 16 chunks, swizzle chunk ^ (row&15)
        const int row = c >> 4, gc = (c & 15) ^ (row & 15);
        gl2lds16(vt + ((size_t)bh * DKH + row) * S_LEN + kt * 128 + gc * 8,
                 &sV[c * 8]);
      }
    }
    __syncthreads();

    // S^T and P^T, per 16-key block
#pragma unroll
    for (int kb = 0; kb < 8; ++kb) {
      const int krow = kb * 16 + ll;
      const bf16x8 ak0 = ldfrag(&sK[krow * 64 + (lg ^ (ll & 7)) * 8]);
      const bf16x8 ak1 = ldfrag(&sK[krow * 64 + ((4 + lg) ^ (ll & 7)) * 8]);
      f32x4 s0 = {}, s1 = {};
      s0 = mfma16(ak0, aq[0][0], s0);
      s0 = mfma16(ak1, aq[0][1], s0);
      s1 = mfma16(ak0, aq[1][0], s1);
      s1 = mfma16(ak1, aq[1][1], s1);
      const int poff = ll * 128 + ((kb ^ (ll & 7)) * 4 + lg) * 4;
      u16x4 pk;
      float ps = 0.f;
#pragma unroll
      for (int r = 0; r < 4; ++r) {
        const float p = __builtin_amdgcn_exp2f(s0[r]);
        ps += p; pk[r] = f2bf(p);
      }
      l_part[0] += ps;
      *(u16x4*)&sP0[poff] = pk;
      ps = 0.f;
#pragma unroll
      for (int r = 0; r < 4; ++r) {
        const float p = __builtin_amdgcn_exp2f(s1[r]);
        ps += p; pk[r] = f2bf(p);
      }
      l_part[1] += ps;
      *(u16x4*)&sP1[poff] = pk;
    }

    // O^T += V^T . P^T   (same-wave LDS ordering: DS ops complete in order)
    bf16x8 bp0[4], bp1[4];
#pragma unroll
    for (int f = 0; f < 4; ++f) {
      const int kb = f * 2 + (lg >> 1);
      const int off = ll * 128 + ((kb ^ (ll & 7)) * 4 + 2 * (lg & 1)) * 4;
      bp0[f] = ldfrag(&sP0[off]);
      bp1[f] = ldfrag(&sP1[off]);
    }
#pragma unroll
    for (int nt = 0; nt < 4; ++nt) {
      const int vrow = nt * 16 + ll;
#pragma unroll
      for (int f = 0; f < 4; ++f) {
        const bf16x8 av = ldfrag(&sV[vrow * 128 + ((f * 4 + lg) ^ ll) * 8]);
        oT[0][nt] = mfma16(av, bp0[f], oT[0][nt]);
        oT[1][nt] = mfma16(av, bp1[f], oT[1][nt]);
      }
    }
  }

  const int b = bh >> 4, h = bh & 15;
#pragma unroll
  for (int qt = 0; qt < 2; ++qt) {
    float lv = l_part[qt];
    lv += __shfl_xor(lv, 16, 64);
    lv += __shfl_xor(lv, 32, 64);
    const float inv = 1.0f / lv;
    const int srow = q_blk + w * 32 + qt * 16 + ll;
#pragma unroll
    for (int nt = 0; nt < 4; ++nt) {
      u16x4 o;
#pragma unroll
      for (int r = 0; r < 4; ++r) o[r] = f2bf(oT[qt][nt][r] * inv);
      *(u16x4*)&ctx[((size_t)((b * S_LEN + srow) * NH + h)) * DKH + nt * 16 + lg * 4] = o;
    }
  }
}

// ---------------- output projection GEMM ----------------
// 64x64 tile, BK=64, 4 waves (2x2 of 32x32). Grid (16,64) = 1024 blocks
// = 4 blocks/CU -> ~16 waves/CU for latency hiding.
__global__ __launch_bounds__(256) void out_gemm(
    const u16* __restrict__ Am, const u16* __restrict__ W,
    const float* __restrict__ bo, float* __restrict__ out) {
  __shared__ __align__(16) u16 sA[64 * 64];   // 8 KB
  __shared__ __align__(16) u16 sB[64 * 64];   // 8 KB
  const int t = threadIdx.x;
  const int l = t & 63, w = t >> 6;
  const int ll = l & 15, lg = l >> 4;
  const int nb = blockIdx.x;  // 0..15
  const int mb = blockIdx.y;  // 0..63
  const int wr = (w >> 1) * 32, wc = (w & 1) * 32;

  f32x4 acc[2][2] = {};
  for (int kt = 0; kt < 16; ++kt) {
    const int k0 = kt * 64;
    __syncthreads();
#pragma unroll
    for (int i = 0; i < 2; ++i) {
      const int c = i * 256 + t;               // 512 chunks per buffer
      const int row = c >> 3;
      const int gc = (c & 7) ^ (row & 7);
      gl2lds16(Am + (size_t)(mb * 64 + row) * DEMB + k0 + gc * 8, &sA[c * 8]);
      gl2lds16(W + (size_t)(nb * 64 + row) * DEMB + k0 + gc * 8, &sB[c * 8]);
    }
    __syncthreads();
#pragma unroll
    for (int sub = 0; sub < 2; ++sub) {
      bf16x8 af[2], bfr[2];
#pragma unroll
      for (int i2 = 0; i2 < 2; ++i2) {
        const int row = wr + i2 * 16 + ll;
        af[i2] = ldfrag(&sA[row * 64 + ((sub * 4 + lg) ^ (row & 7)) * 8]);
      }
#pragma unroll
      for (int j2 = 0; j2 < 2; ++j2) {
        const int row = wc + j2 * 16 + ll;
        bfr[j2] = ldfrag(&sB[row * 64 + ((sub * 4 + lg) ^ (row & 7)) * 8]);
      }
#pragma unroll
      for (int i2 = 0; i2 < 2; ++i2)
#pragma unroll
        for (int j2 = 0; j2 < 2; ++j2)
          acc[i2][j2] = mfma16(af[i2], bfr[j2], acc[i2][j2]);
    }
  }

#pragma unroll
  for (int j2 = 0; j2 < 2; ++j2) {
    const int ncol = nb * 64 + wc + j2 * 16 + ll;
    const float bb = bo[ncol];
#pragma unroll
    for (int i2 = 0; i2 < 2; ++i2) {
#pragma unroll
      for (int r = 0; r < 4; ++r) {
        const int mrow = mb * 64 + wr + i2 * 16 + lg * 4 + r;
        out[(size_t)mrow * DEMB + ncol] = acc[i2][j2][r] + bb;
      }
    }
  }
}

extern "C" void kernel_launch(void* const* d_in, const int* in_sizes, int n_in,
                              void* d_out, int out_size, void* d_ws,
                              size_t ws_size, hipStream_t stream) {
  (void)in_sizes; (void)n_in; (void)out_size; (void)ws_size;
  const float* Q  = (const float*)d_in[0];
  const float* K  = (const float*)d_in[1];
  const float* V  = (const float*)d_in[2];
  const float* WQ = (const float*)d_in[3];
  const float* bQ = (const float*)d_in[4];
  const float* WK = (const float*)d_in[5];
  const float* bK = (const float*)d_in[6];
  const float* WV = (const float*)d_in[7];
  const float* bV = (const float*)d_in[8];
  const float* WO = (const float*)d_in[9];
  const float* bO = (const float*)d_in[10];
  float* out = (float*)d_out;

  // workspace (u16 units): 4M(Wqkv+Wo) + 12M(qin/kin/vin) + 16M(qh/kh/vt/ctx)
  // = 32M u16 = 64 MiB
  u16* ws   = (u16*)d_ws;
  u16* Wqkv = ws;                        // [3072,1024]
  u16* Wo   = Wqkv + 3072 * 1024;        // [1024,1024]
  u16* qin  = Wo + 1024 * 1024;          // [4096,1024] bf16 activations
  u16* kin  = qin + (size_t)MTOT * DEMB;
  u16* vin  = kin + (size_t)MTOT * DEMB;
  u16* qh   = vin + (size_t)MTOT * DEMB; // [BH=32][S=2048][64] (pre-scaled)
  u16* kh   = qh + 32 * 2048 * 64;       // [BH][S][64]
  u16* vt   = kh + 32 * 2048 * 64;       // [BH][64][S] (transposed)
  u16* ctx  = vt + 32 * 2048 * 64;       // [B][S][H][64] == [4096,1024]

  const int WN = DEMB * DEMB;            // 1,048,576
  const int AN = MTOT * DEMB;            // 4,194,304
  cvt_bf16<<<WN / 1024, 256, 0, stream>>>(WQ, Wqkv, WN);
  cvt_bf16<<<WN / 1024, 256, 0, stream>>>(WK, Wqkv + WN, WN);
  cvt_bf16<<<WN / 1024, 256, 0, stream>>>(WV, Wqkv + 2 * WN, WN);
  cvt_bf16<<<WN / 1024, 256, 0, stream>>>(WO, Wo, WN);
  cvt_bf16<<<AN / 1024, 256, 0, stream>>>(Q, qin, AN);
  cvt_bf16<<<AN / 1024, 256, 0, stream>>>(K, kin, AN);
  cvt_bf16<<<AN / 1024, 256, 0, stream>>>(V, vin, AN);

  qkv_gemm<<<dim3(24, 32), 256, 0, stream>>>(qin, kin, vin, Wqkv, bQ, bK, bV,
                                             qh, kh, vt);
  attn_kernel<<<dim3(16, 32), 256, 0, stream>>>(qh, kh, vt, ctx);
  out_gemm<<<dim3(16, 64), 256, 0, stream>>>(ctx, Wo, bO, out);
}

// Round 5
// 250.054 us; speedup vs baseline: 1.4026x; 1.0280x over previous
//
#include <hip/hip_runtime.h>
#include <cstdint>
#include <cstddef>

// Problem constants: B=2, S=2048, D=1024, H=16, dk=64. M = B*S = 4096.
#define S_LEN 2048
#define NH    16
#define DKH   64
#define DEMB  1024
#define MTOT  4096

typedef float f32x4 __attribute__((ext_vector_type(4)));
typedef __bf16 bf16x8 __attribute__((ext_vector_type(8)));
typedef unsigned short u16;
typedef unsigned int u32;
typedef u16 u16x8 __attribute__((ext_vector_type(8)));
typedef u16 u16x4 __attribute__((ext_vector_type(4)));
typedef u32 u32x2 __attribute__((ext_vector_type(2)));

static __device__ __forceinline__ u16 f2bf(float f) {
  u32 u = __builtin_bit_cast(u32, f);
  u += 0x7fffu + ((u >> 16) & 1u);          // RNE
  return (u16)(u >> 16);
}
static __device__ __forceinline__ bf16x8 ldfrag(const u16* p) {
  return __builtin_bit_cast(bf16x8, *(const u16x8*)p);
}
static __device__ __forceinline__ f32x4 mfma16(bf16x8 a, bf16x8 b, f32x4 c) {
  return __builtin_amdgcn_mfma_f32_16x16x32_bf16(a, b, c, 0, 0, 0);
}
static __device__ __forceinline__ void gl2lds16(const void* g, void* l) {
  __builtin_amdgcn_global_load_lds((__attribute__((address_space(1))) void*)g,
                                   (__attribute__((address_space(3))) void*)l,
                                   16, 0, 0);
}
// pack two fp32 -> two bf16 (round-half-up) in one v_perm
static __device__ __forceinline__ u32 pkbf(float hi, float lo) {
  u32 a = __builtin_bit_cast(u32, hi) + 0x8000u;
  u32 b = __builtin_bit_cast(u32, lo) + 0x8000u;
  return __builtin_amdgcn_perm(a, b, 0x07060302u);
}

// 1/sqrt(dk) * log2(e): folded into the Q projection so attention scores are
// already in the exp2 domain.
#define SCL_Q (0.125f * 1.44269504088896340736f)

// ---------------- fp32 -> bf16 convert (weights + activations) ----------------
__global__ __launch_bounds__(256) void cvt_bf16(const float* __restrict__ s,
                                                u16* __restrict__ d, int n) {
  int i = (blockIdx.x * 256 + threadIdx.x) * 4;
  if (i >= n) return;
  f32x4 f = *(const f32x4*)(s + i);
  u16x4 o;
  o[0] = f2bf(f[0]); o[1] = f2bf(f[1]); o[2] = f2bf(f[2]); o[3] = f2bf(f[3]);
  *(u16x4*)(d + i) = o;
}

// ---------------- fused QKV projection GEMM (pure bf16, m97 structure) -------
__global__ __launch_bounds__(256) void qkv_gemm(
    const u16* __restrict__ qin, const u16* __restrict__ kin,
    const u16* __restrict__ vin, const u16* __restrict__ W,
    const float* __restrict__ bq, const float* __restrict__ bk,
    const float* __restrict__ bv,
    u16* __restrict__ qh, u16* __restrict__ kh, u16* __restrict__ vt) {
  __shared__ __align__(16) u16 sA[128 * 32];    // 8 KB
  __shared__ __align__(16) u16 sB[128 * 32];    // 8 KB
  const int t = threadIdx.x;
  const int l = t & 63, w = t >> 6;
  const int ll = l & 15, lg = l >> 4;
  const int nb = blockIdx.x;           // 0..23 (N = 3072)
  const int mb = blockIdx.y;           // 0..31 (M = 4096)
  const int which = nb >> 3;           // 0=Q,1=K,2=V
  const u16* A = (which == 0) ? qin : ((which == 1) ? kin : vin);
  const int wr = (w >> 1) * 64, wc = (w & 1) * 64;

  f32x4 acc[4][4] = {};

  for (int kt = 0; kt < 32; ++kt) {
    const int k0 = kt * 32;
    __syncthreads();
#pragma unroll
    for (int i = 0; i < 2; ++i) {
      const int c = i * 256 + t;                 // 16B chunk 0..511
      const int row = c >> 2;                    // 0..127
      const int gc = (c & 3) ^ ((row >> 1) & 3); // global col-chunk
      gl2lds16(A + (size_t)(mb * 128 + row) * DEMB + k0 + gc * 8, &sA[c * 8]);
      gl2lds16(W + (size_t)(nb * 128 + row) * DEMB + k0 + gc * 8, &sB[c * 8]);
    }
    __syncthreads();

    bf16x8 af[4], bfr[4];
#pragma unroll
    for (int i2 = 0; i2 < 4; ++i2) {
      const int row = wr + i2 * 16 + ll;
      af[i2] = ldfrag(&sA[row * 32 + (lg ^ ((row >> 1) & 3)) * 8]);
    }
#pragma unroll
    for (int j2 = 0; j2 < 4; ++j2) {
      const int row = wc + j2 * 16 + ll;
      bfr[j2] = ldfrag(&sB[row * 32 + (lg ^ ((row >> 1) & 3)) * 8]);
    }
#pragma unroll
    for (int i2 = 0; i2 < 4; ++i2)
#pragma unroll
      for (int j2 = 0; j2 < 4; ++j2)
        acc[i2][j2] = mfma16(af[i2], bfr[j2], acc[i2][j2]);
  }

  const float* bias = (which == 0) ? bq : ((which == 1) ? bk : bv);
  const int b = (mb * 128) >> 11;                // tile never crosses batch

  if (which == 2) {
    // V: register scatter to [bh][dk][s]; 4 consecutive s per u16x4 store
#pragma unroll
    for (int j2 = 0; j2 < 4; ++j2) {
      const int nl = (nb * 128 + wc + j2 * 16 + ll) & 1023;
      const int h = nl >> 6, dk = nl & 63;
      const float bb = bias[nl];
      u16* base = vt + ((size_t)((b * NH + h) * DKH + dk)) * S_LEN;
#pragma unroll
      for (int i2 = 0; i2 < 4; ++i2) {
        const int s = (mb * 128 + wr + i2 * 16 + lg * 4) & 2047;
        u16x4 pk;
#pragma unroll
        for (int r = 0; r < 4; ++r) pk[r] = f2bf(acc[i2][j2][r] + bb);
        *(u16x4*)&base[s] = pk;
      }
    }
  } else {
    u16* outp = (which == 0) ? qh : kh;
    const float scl = (which == 0) ? SCL_Q : 1.0f;
#pragma unroll
    for (int j2 = 0; j2 < 4; ++j2) {
      const int nl = (nb * 128 + wc + j2 * 16 + ll) & 1023;
      const int h = nl >> 6, dk = nl & 63;
      const float bb = bias[nl];
#pragma unroll
      for (int i2 = 0; i2 < 4; ++i2) {
#pragma unroll
        for (int r = 0; r < 4; ++r) {
          const int s = (mb * 128 + wr + i2 * 16 + lg * 4 + r) & 2047;
          const float val = (acc[i2][j2][r] + bb) * scl;
          outp[((size_t)((b * NH + h) * S_LEN + s)) * DKH + dk] = f2bf(val);
        }
      }
    }
  }
}

// ---------------- flash attention (transposed formulation) ----------------
// One block = one (b,h) x 128 q-rows (wave w owns q rows w*32..w*32+31, as
// 2 q-tiles of 16). Key tile = 128, processed in two 64-key halves that
// reuse one per-(wave,qt) P buffer.  S^T = K.Q^T, fixed-max exp2 softmax,
// O^T = V^T.P^T.
// sP banking: row stride 68 u16 (136 B == 2 banks mod 32) ->
//   write (8 B per lane): bank = 2*ll + kbl*8 + lg*2  -> bijection onto the
//   16 even bank-pairs within every 16-lane phase group (conflict-free);
//   reads are 8 B pairs with bank = 2*ll + const (also conflict-free).
// This replaces the R4 layout whose writes were 4-way conflicted (192
// extra LDS cycles per wave-iter = the measured 6.29M SQ_LDS_BANK_CONFLICT).
__global__ __launch_bounds__(256) void attn_kernel(
    const u16* __restrict__ qh, const u16* __restrict__ kh,
    const u16* __restrict__ vt, u16* __restrict__ ctx) {
  __shared__ __align__(16) u16 sK[128 * 64];      // [key][dk]  16 KB
  __shared__ __align__(16) u16 sV[64 * 128];      // [dk][key]  16 KB
  __shared__ __align__(16) u16 sP[4][2][16 * 68]; // per-(wave,qt) [q][64key+pad]
  const int t = threadIdx.x;
  const int l = t & 63, w = t >> 6;
  const int ll = l & 15, lg = l >> 4;
  const int q_blk = blockIdx.x * 128;
  const int bh = blockIdx.y;

  // Q fragments (B-operand layout == A layout: q=ll, dk=f*32+lg*8..+7)
  bf16x8 aq[2][2];
#pragma unroll
  for (int qt = 0; qt < 2; ++qt) {
    const u16* qbase = qh + ((size_t)bh * S_LEN + q_blk + w * 32 + qt * 16 + ll) * DKH;
    aq[qt][0] = ldfrag(qbase + lg * 8);
    aq[qt][1] = ldfrag(qbase + 32 + lg * 8);
  }

  f32x4 oT[2][4] = {};        // [qt][dk-tile]; C layout: col=q=ll, row=dk
  float l_part[2] = {0.f, 0.f};

  u16* sP0 = &sP[w][0][0];
  u16* sP1 = &sP[w][1][0];

  for (int kt = 0; kt < 16; ++kt) {
    __syncthreads();
#pragma unroll
    for (int i = 0; i < 4; ++i) {
      const int c = i * 256 + t;                  // 16B chunk 0..1023
      {  // sK: 128 rows x 8 chunks, swizzle chunk ^ (row&7)
        const int row = c >> 3, gc = (c & 7) ^ (row & 7);
        gl2lds16(kh + ((size_t)bh * S_LEN + kt * 128 + row) * DKH + gc * 8,
                 &sK[c * 8]);
      }
      {  // sV: 64 rows x 16 chunks, swizzle chunk ^ (row&15)
        const int row = c >> 4, gc = (c & 15) ^ (row & 15);
        gl2lds16(vt + ((size_t)bh * DKH + row) * S_LEN + kt * 128 + gc * 8,
                 &sV[c * 8]);
      }
    }
    __syncthreads();

#pragma unroll
    for (int h = 0; h < 2; ++h) {
      // ---- S^T + P^T for keys h*64 .. h*64+63 ----
#pragma unroll
      for (int kbl = 0; kbl < 4; ++kbl) {
        const int kb = h * 4 + kbl;
        const int krow = kb * 16 + ll;
        const bf16x8 ak0 = ldfrag(&sK[krow * 64 + (lg ^ (ll & 7)) * 8]);
        const bf16x8 ak1 = ldfrag(&sK[krow * 64 + ((4 + lg) ^ (ll & 7)) * 8]);
        f32x4 s0 = {}, s1 = {};
        s0 = mfma16(ak0, aq[0][0], s0);
        s0 = mfma16(ak1, aq[0][1], s0);
        s1 = mfma16(ak0, aq[1][0], s1);
        s1 = mfma16(ak1, aq[1][1], s1);
        const int poff = ll * 68 + kbl * 16 + lg * 4;   // u16 units, 8B aligned
        {
          const float p0 = __builtin_amdgcn_exp2f(s0[0]);
          const float p1 = __builtin_amdgcn_exp2f(s0[1]);
          const float p2 = __builtin_amdgcn_exp2f(s0[2]);
          const float p3 = __builtin_amdgcn_exp2f(s0[3]);
          l_part[0] += (p0 + p1) + (p2 + p3);
          u32x2 pk; pk[0] = pkbf(p1, p0); pk[1] = pkbf(p3, p2);
          *(u32x2*)&sP0[poff] = pk;
        }
        {
          const float p0 = __builtin_amdgcn_exp2f(s1[0]);
          const float p1 = __builtin_amdgcn_exp2f(s1[1]);
          const float p2 = __builtin_amdgcn_exp2f(s1[2]);
          const float p3 = __builtin_amdgcn_exp2f(s1[3]);
          l_part[1] += (p0 + p1) + (p2 + p3);
          u32x2 pk; pk[0] = pkbf(p1, p0); pk[1] = pkbf(p3, p2);
          *(u32x2*)&sP1[poff] = pk;
        }
      }

      // ---- O^T += V^T . P^T for this half (intra-wave LDS ordering) ----
      bf16x8 bp[2][2];
#pragma unroll
      for (int fl = 0; fl < 2; ++fl) {
        const int off = ll * 68 + fl * 32 + lg * 8;
        const u16x4 lo0 = *(const u16x4*)&sP0[off];
        const u16x4 hi0 = *(const u16x4*)&sP0[off + 4];
        bp[0][fl] = __builtin_bit_cast(bf16x8,
            __builtin_shufflevector(lo0, hi0, 0, 1, 2, 3, 4, 5, 6, 7));
        const u16x4 lo1 = *(const u16x4*)&sP1[off];
        const u16x4 hi1 = *(const u16x4*)&sP1[off + 4];
        bp[1][fl] = __builtin_bit_cast(bf16x8,
            __builtin_shufflevector(lo1, hi1, 0, 1, 2, 3, 4, 5, 6, 7));
      }
#pragma unroll
      for (int nt = 0; nt < 4; ++nt) {
        const int vrow = nt * 16 + ll;
#pragma unroll
        for (int fl = 0; fl < 2; ++fl) {
          const int fg = h * 2 + fl;
          const bf16x8 av = ldfrag(&sV[vrow * 128 + ((fg * 4 + lg) ^ ll) * 8]);
          oT[0][nt] = mfma16(av, bp[0][fl], oT[0][nt]);
          oT[1][nt] = mfma16(av, bp[1][fl], oT[1][nt]);
        }
      }
    }
  }

  const int b = bh >> 4, h = bh & 15;
#pragma unroll
  for (int qt = 0; qt < 2; ++qt) {
    float lv = l_part[qt];
    lv += __shfl_xor(lv, 16, 64);
    lv += __shfl_xor(lv, 32, 64);
    const float inv = 1.0f / lv;
    const int srow = q_blk + w * 32 + qt * 16 + ll;
#pragma unroll
    for (int nt = 0; nt < 4; ++nt) {
      u16x4 o;
#pragma unroll
      for (int r = 0; r < 4; ++r) o[r] = f2bf(oT[qt][nt][r] * inv);
      *(u16x4*)&ctx[((size_t)((b * S_LEN + srow) * NH + h)) * DKH + nt * 16 + lg * 4] = o;
    }
  }
}

// ---------------- output projection GEMM ----------------
// 64x64 tile, BK=64, 4 waves (2x2 of 32x32). Grid (16,64) = 1024 blocks
// = 4 blocks/CU -> ~16 waves/CU for latency hiding.
__global__ __launch_bounds__(256) void out_gemm(
    const u16* __restrict__ Am, const u16* __restrict__ W,
    const float* __restrict__ bo, float* __restrict__ out) {
  __shared__ __align__(16) u16 sA[64 * 64];   // 8 KB
  __shared__ __align__(16) u16 sB[64 * 64];   // 8 KB
  const int t = threadIdx.x;
  const int l = t & 63, w = t >> 6;
  const int ll = l & 15, lg = l >> 4;
  const int nb = blockIdx.x;  // 0..15
  const int mb = blockIdx.y;  // 0..63
  const int wr = (w >> 1) * 32, wc = (w & 1) * 32;

  f32x4 acc[2][2] = {};
  for (int kt = 0; kt < 16; ++kt) {
    const int k0 = kt * 64;
    __syncthreads();
#pragma unroll
    for (int i = 0; i < 2; ++i) {
      const int c = i * 256 + t;               // 512 chunks per buffer
      const int row = c >> 3;
      const int gc = (c & 7) ^ (row & 7);
      gl2lds16(Am + (size_t)(mb * 64 + row) * DEMB + k0 + gc * 8, &sA[c * 8]);
      gl2lds16(W + (size_t)(nb * 64 + row) * DEMB + k0 + gc * 8, &sB[c * 8]);
    }
    __syncthreads();
#pragma unroll
    for (int sub = 0; sub < 2; ++sub) {
      bf16x8 af[2], bfr[2];
#pragma unroll
      for (int i2 = 0; i2 < 2; ++i2) {
        const int row = wr + i2 * 16 + ll;
        af[i2] = ldfrag(&sA[row * 64 + ((sub * 4 + lg) ^ (row & 7)) * 8]);
      }
#pragma unroll
      for (int j2 = 0; j2 < 2; ++j2) {
        const int row = wc + j2 * 16 + ll;
        bfr[j2] = ldfrag(&sB[row * 64 + ((sub * 4 + lg) ^ (row & 7)) * 8]);
      }
#pragma unroll
      for (int i2 = 0; i2 < 2; ++i2)
#pragma unroll
        for (int j2 = 0; j2 < 2; ++j2)
          acc[i2][j2] = mfma16(af[i2], bfr[j2], acc[i2][j2]);
    }
  }

#pragma unroll
  for (int j2 = 0; j2 < 2; ++j2) {
    const int ncol = nb * 64 + wc + j2 * 16 + ll;
    const float bb = bo[ncol];
#pragma unroll
    for (int i2 = 0; i2 < 2; ++i2) {
#pragma unroll
      for (int r = 0; r < 4; ++r) {
        const int mrow = mb * 64 + wr + i2 * 16 + lg * 4 + r;
        out[(size_t)mrow * DEMB + ncol] = acc[i2][j2][r] + bb;
      }
    }
  }
}

extern "C" void kernel_launch(void* const* d_in, const int* in_sizes, int n_in,
                              void* d_out, int out_size, void* d_ws,
                              size_t ws_size, hipStream_t stream) {
  (void)in_sizes; (void)n_in; (void)out_size; (void)ws_size;
  const float* Q  = (const float*)d_in[0];
  const float* K  = (const float*)d_in[1];
  const float* V  = (const float*)d_in[2];
  const float* WQ = (const float*)d_in[3];
  const float* bQ = (const float*)d_in[4];
  const float* WK = (const float*)d_in[5];
  const float* bK = (const float*)d_in[6];
  const float* WV = (const float*)d_in[7];
  const float* bV = (const float*)d_in[8];
  const float* WO = (const float*)d_in[9];
  const float* bO = (const float*)d_in[10];
  float* out = (float*)d_out;

  // workspace (u16 units): 4M(Wqkv+Wo) + 12M(qin/kin/vin) + 16M(qh/kh/vt/ctx)
  // = 32M u16 = 64 MiB
  u16* ws   = (u16*)d_ws;
  u16* Wqkv = ws;                        // [3072,1024]
  u16* Wo   = Wqkv + 3072 * 1024;        // [1024,1024]
  u16* qin  = Wo + 1024 * 1024;          // [4096,1024] bf16 activations
  u16* kin  = qin + (size_t)MTOT * DEMB;
  u16* vin  = kin + (size_t)MTOT * DEMB;
  u16* qh   = vin + (size_t)MTOT * DEMB; // [BH=32][S=2048][64] (pre-scaled)
  u16* kh   = qh + 32 * 2048 * 64;       // [BH][S][64]
  u16* vt   = kh + 32 * 2048 * 64;       // [BH][64][S] (transposed)
  u16* ctx  = vt + 32 * 2048 * 64;       // [B][S][H][64] == [4096,1024]

  const int WN = DEMB * DEMB;            // 1,048,576
  const int AN = MTOT * DEMB;            // 4,194,304
  cvt_bf16<<<WN / 1024, 256, 0, stream>>>(WQ, Wqkv, WN);
  cvt_bf16<<<WN / 1024, 256, 0, stream>>>(WK, Wqkv + WN, WN);
  cvt_bf16<<<WN / 1024, 256, 0, stream>>>(WV, Wqkv + 2 * WN, WN);
  cvt_bf16<<<WN / 1024, 256, 0, stream>>>(WO, Wo, WN);
  cvt_bf16<<<AN / 1024, 256, 0, stream>>>(Q, qin, AN);
  cvt_bf16<<<AN / 1024, 256, 0, stream>>>(K, kin, AN);
  cvt_bf16<<<AN / 1024, 256, 0, stream>>>(V, vin, AN);

  qkv_gemm<<<dim3(24, 32), 256, 0, stream>>>(qin, kin, vin, Wqkv, bQ, bK, bV,
                                             qh, kh, vt);
  attn_kernel<<<dim3(16, 32), 256, 0, stream>>>(qh, kh, vt, ctx);
  out_gemm<<<dim3(16, 64), 256, 0, stream>>>(ctx, Wo, bO, out);
}